// Round 6
// baseline (3228.695 us; speedup 1.0000x reference)
//
#include <hip/hip_runtime.h>
#include <hip/hip_bf16.h>
#include <stdint.h>
#include <stddef.h>

#define NW    4096
#define LSEQ  24
#define HDIM  512
#define DWG   300
#define DCC   128
#define VCC   100
#define G4H   2048
#define CATD  812
#define HIDD  512
#define NOUT  5
#define NBLK  128   // LSTM blocks (32 rows each, no cross-block deps)

typedef __bf16 bf16x8 __attribute__((ext_vector_type(8)));
typedef float  f32x16 __attribute__((ext_vector_type(16)));

__device__ __forceinline__ float frcp(float x) { return __builtin_amdgcn_rcpf(x); }
__device__ __forceinline__ float sigf(float x) { return frcp(1.0f + __expf(-x)); }
__device__ __forceinline__ float tanh_fast(float x) { return fmaf(2.0f, frcp(1.0f + __expf(-2.0f * x)), -1.0f); }

// async 16B global->LDS; LDS dest is wave-uniform base + lane*16 (m104)
__device__ __forceinline__ void gload16(const void* g, void* l) {
    __builtin_amdgcn_global_load_lds(
        (const __attribute__((address_space(1))) void*)g,
        (__attribute__((address_space(3))) void*)l, 16, 0, 0);
}

// ---- retile W_hh f32 [2048][512] -> bf16 swizzled panels ----
// panel(a=pass,kp) 32KB at ((a*32+kp)<<15): holds gates {a, a+2} for k in [kp*16,kp*16+16).
// within panel: pos = (g>>1)*512 + col; byte = ((pos<<5) + kh*16) ^ ((pos&7)<<4).
// XOR makes the 32-lane ds_read_b128 column-slice tile all 32 banks (conflict-free).
__global__ void k_convert_wtile(const float* __restrict__ whh, __hip_bfloat16* __restrict__ wt) {
    const int tid = blockIdx.x * 256 + threadIdx.x;   // 65536 = j(2048) x kp(32)
    const int j = tid >> 5, kp = tid & 31;
    const int g = j >> 9, col = j & 511;
    const int a = g & 1, gp = g >> 1;
    const int pos = (gp << 9) + col;
    const float* src = whh + (size_t)j * HDIM + kp * 16;
    char* pbase = (char*)wt + ((a * 32 + kp) << 15);
#pragma unroll
    for (int kh = 0; kh < 2; ++kh) {
        union { bf16x8 v; __hip_bfloat16 e[8]; } u;
#pragma unroll
        for (int i = 0; i < 2; ++i) {
            const float4 f = *reinterpret_cast<const float4*>(src + kh * 8 + i * 4);
            u.e[i * 4 + 0] = __float2bfloat16(f.x);
            u.e[i * 4 + 1] = __float2bfloat16(f.y);
            u.e[i * 4 + 2] = __float2bfloat16(f.z);
            u.e[i * 4 + 3] = __float2bfloat16(f.w);
        }
        const int dst = ((pos << 5) + (kh << 4)) ^ ((pos & 7) << 4);
        *reinterpret_cast<bf16x8*>(pbase + dst) = u.v;
    }
}

// ---- char_proj[c][j] = char_embed[c,:] @ W_ih[j,:] + b_ih[j] + b_hh[j]  (bf16 out) ----
__global__ void k_char_proj(const float* __restrict__ cemb, const float* __restrict__ wih,
                            const float* __restrict__ bih, const float* __restrict__ bhh,
                            __hip_bfloat16* __restrict__ cproj) {
    __shared__ float emb[DCC];
    const int c = blockIdx.x;
    if (threadIdx.x < DCC) emb[threadIdx.x] = cemb[c * DCC + threadIdx.x];
    __syncthreads();
    for (int j = threadIdx.x; j < G4H; j += blockDim.x) {
        const float* w = wih + (size_t)j * DCC;
        float acc = bih[j] + bhh[j];
#pragma unroll 4
        for (int k = 0; k < DCC; ++k) acc = fmaf(emb[k], w[k], acc);
        cproj[(size_t)c * G4H + j] = __float2bfloat16(acc);
    }
}

// ---- LSTM: 128 blocks x 512 thr (8 waves, 2/SIMD -> 256-reg budget, no spill).
// LDS 128KB: [0,64K) h dbuf (swizzled), [64K,128K) W panel dbuf (2x32KB).
// Per step: 64 phases (passA kp0..31 gates i,g; passB kp0..31 gates f,o).
// Phase: issue 4 global_load_lds (next panel) -> ds_read A+4B frags -> 4 MFMA -> syncthreads.
__global__ void __launch_bounds__(512, 2) k_lstm_block(
        const __hip_bfloat16* __restrict__ wt,     // 64 swizzled 32KB panels
        const __hip_bfloat16* __restrict__ cproj,  // [100][2048] bf16
        const int* __restrict__ cidx,              // [NW][LSEQ]
        const int* __restrict__ clen,              // [NW]
        float* __restrict__ pchar) {               // [NBLK][512] partial col sums
    extern __shared__ char lds[];
    char* ldsW = lds + 65536;
    const int b = blockIdx.x;
    const int tid = threadIdx.x;
    const int w = tid >> 6, lane = tid & 63;
    const int l31 = lane & 31, lhi = lane >> 5;
    const int n0 = b * 32;
    const int xr = (l31 & 15) << 4;

    int len16[16];
#pragma unroll
    for (int q = 0; q < 16; ++q) {
        const int rin = (q & 3) + ((q >> 2) << 3) + (lhi << 2);
        len16[q] = clen[n0 + rin];
    }
    float cs[2][16];
#pragma unroll
    for (int p = 0; p < 2; ++p)
#pragma unroll
        for (int q = 0; q < 16; ++q) cs[p][q] = 0.0f;

    // B-frag byte offsets within a panel: constant per thread per (p,g)
    int bofs[2][2];
#pragma unroll
    for (int p = 0; p < 2; ++p)
#pragma unroll
        for (int g = 0; g < 2; ++g) {
            const int pos = (g << 9) + ((w << 1) + p) * 32 + l31;
            bofs[p][g] = (((pos << 5) + (lhi << 4)) ^ ((pos & 7) << 4));
        }

    // ---- prestage panel A0 into W buf 0 ----
    {
        const char* gs = (const char*)wt + (w << 12) + (lane << 4);
        char* ls = ldsW + (w << 12);
#pragma unroll
        for (int i = 0; i < 4; ++i) gload16(gs + i * 1024, ls + i * 1024);
    }

    // ---- t = 0: gates from cproj only (h=0, c=0); write h1 into hbuf[1] ----
    {
        char* wl = lds + (1 << 15);
#pragma unroll
        for (int p = 0; p < 2; ++p) {
            const int colh = ((w << 1) + p) * 32 + l31;
#pragma unroll
            for (int q = 0; q < 16; ++q) {
                const int rin = (q & 3) + ((q >> 2) << 3) + (lhi << 2);
                float hv = 0.0f;
                if (0 < len16[q]) {
                    const int ci = cidx[(n0 + rin) * LSEQ];
                    const __hip_bfloat16* cp = cproj + ((size_t)ci << 11) + colh;
                    const float i_s = sigf(__bfloat162float(cp[0]));
                    const float g_t = tanh_fast(__bfloat162float(cp[1024]));
                    const float o_s = sigf(__bfloat162float(cp[1536]));
                    const float cn = i_s * g_t;
                    cs[p][q] = cn;
                    hv = o_s * tanh_fast(cn);
                }
                *reinterpret_cast<__hip_bfloat16*>(
                    wl + (rin << 10) + ((colh << 1) ^ ((rin & 15) << 4))) = __float2bfloat16(hv);
            }
        }
    }
    __syncthreads();   // h1 visible + prestage drained

    int soff = 32768;  // wt byte offset of next panel to stage (A1)
    int cur = 0;

    for (int t = 1; t < LSEQ; ++t) {
        const char* rl = lds + ((t & 1) << 15) + (l31 << 10);
        float ig[2][16];

        // ---------- pass A: gates i, g ----------
        {
            f32x16 acc[2][2] = {};
            for (int kp = 0; kp < 32; ++kp) {
                {   // stage next panel
                    const char* gs = (const char*)wt + soff + (w << 12) + (lane << 4);
                    char* ls = ldsW + ((cur ^ 1) << 15) + (w << 12);
#pragma unroll
                    for (int i = 0; i < 4; ++i) gload16(gs + i * 1024, ls + i * 1024);
                    soff = (soff + 32768) & ((1 << 21) - 1);
                }
                const char* wb = ldsW + (cur << 15);
                const bf16x8 a = *reinterpret_cast<const bf16x8*>(
                    rl + (((kp << 5) | (lhi << 4)) ^ xr));
#pragma unroll
                for (int p = 0; p < 2; ++p)
#pragma unroll
                    for (int g = 0; g < 2; ++g) {
                        const bf16x8 bv = *reinterpret_cast<const bf16x8*>(wb + bofs[p][g]);
                        acc[p][g] = __builtin_amdgcn_mfma_f32_32x32x16_bf16(a, bv, acc[p][g], 0, 0, 0);
                    }
                __syncthreads();
                cur ^= 1;
            }
            // epilogue A: ig = sig(i) * tanh(g), only for active rows
#pragma unroll
            for (int p = 0; p < 2; ++p) {
                const int colh = ((w << 1) + p) * 32 + l31;
#pragma unroll
                for (int q = 0; q < 16; ++q) {
                    ig[p][q] = 0.0f;
                    if (t < len16[q]) {
                        const int rin = (q & 3) + ((q >> 2) << 3) + (lhi << 2);
                        const int ci = cidx[(n0 + rin) * LSEQ + t];
                        const __hip_bfloat16* cp = cproj + ((size_t)ci << 11) + colh;
                        const float gi = acc[p][0][q] + __bfloat162float(cp[0]);
                        const float gg = acc[p][1][q] + __bfloat162float(cp[1024]);
                        ig[p][q] = sigf(gi) * tanh_fast(gg);
                    }
                }
            }
        }

        // ---------- pass B: gates f, o + state update ----------
        {
            f32x16 acc[2][2] = {};
            for (int kp = 0; kp < 32; ++kp) {
                {
                    const char* gs = (const char*)wt + soff + (w << 12) + (lane << 4);
                    char* ls = ldsW + ((cur ^ 1) << 15) + (w << 12);
#pragma unroll
                    for (int i = 0; i < 4; ++i) gload16(gs + i * 1024, ls + i * 1024);
                    soff = (soff + 32768) & ((1 << 21) - 1);
                }
                const char* wb = ldsW + (cur << 15);
                const bf16x8 a = *reinterpret_cast<const bf16x8*>(
                    rl + (((kp << 5) | (lhi << 4)) ^ xr));
#pragma unroll
                for (int p = 0; p < 2; ++p)
#pragma unroll
                    for (int g = 0; g < 2; ++g) {
                        const bf16x8 bv = *reinterpret_cast<const bf16x8*>(wb + bofs[p][g]);
                        acc[p][g] = __builtin_amdgcn_mfma_f32_32x32x16_bf16(a, bv, acc[p][g], 0, 0, 0);
                    }
                __syncthreads();
                cur ^= 1;
            }
            // epilogue B: c,h update; write h_{t+1}
            const char* ro = lds + ((t & 1) << 15);
            char* wl = lds + (((t + 1) & 1) << 15);
#pragma unroll
            for (int p = 0; p < 2; ++p) {
                const int colh = ((w << 1) + p) * 32 + l31;
#pragma unroll
                for (int q = 0; q < 16; ++q) {
                    const int rin = (q & 3) + ((q >> 2) << 3) + (lhi << 2);
                    const int sw = (rin << 10) + ((colh << 1) ^ ((rin & 15) << 4));
                    if (t < len16[q]) {
                        const int ci = cidx[(n0 + rin) * LSEQ + t];
                        const __hip_bfloat16* cp = cproj + ((size_t)ci << 11) + colh;
                        const float f_s = sigf(acc[p][0][q] + __bfloat162float(cp[512]));
                        const float o_s = sigf(acc[p][1][q] + __bfloat162float(cp[1536]));
                        const float cn = fmaf(f_s, cs[p][q], ig[p][q]);
                        cs[p][q] = cn;
                        *reinterpret_cast<__hip_bfloat16*>(wl + sw) =
                            __float2bfloat16(o_s * tanh_fast(cn));
                    } else {
                        *reinterpret_cast<__hip_bfloat16*>(wl + sw) =
                            *reinterpret_cast<const __hip_bfloat16*>(ro + sw);
                    }
                }
            }
        }
        __syncthreads();   // h_{t+1} visible for next step
    }

    // final h (h_24) is in hbuf[0]; each thread sums the elements it wrote (no barrier)
#pragma unroll
    for (int p = 0; p < 2; ++p) {
        const int colh = ((w << 1) + p) * 32 + l31;
        float s = 0.0f;
#pragma unroll
        for (int q = 0; q < 16; ++q) {
            if (len16[q] >= 2) {
                const int rin = (q & 3) + ((q >> 2) << 3) + (lhi << 2);
                const int sw = (rin << 10) + ((colh << 1) ^ ((rin & 15) << 4));
                s += __bfloat162float(*reinterpret_cast<const __hip_bfloat16*>(lds + sw));
            }
        }
        s += __shfl_xor(s, 32, 64);
        if (lhi == 0) pchar[b * HDIM + colh] = s;
    }
}

// ---- glove gather column sums, 5x16 partial grid ----
__global__ void k_sum_glove(const float* __restrict__ gt, const int* __restrict__ widx,
                            float* __restrict__ pglove) {
    const int col = blockIdx.x * 64 + (threadIdx.x & 63);
    const int phase = threadIdx.x >> 6;
    const int nbase = blockIdx.y * 256;
    float s = 0.0f;
    if (col < DWG) {
        for (int n = nbase + phase; n < nbase + 256; n += 4) {
            s += gt[(size_t)widx[n] * DWG + col];
        }
    }
    __shared__ float red[256];
    red[threadIdx.x] = s;
    __syncthreads();
    if (phase == 0 && col < DWG) {
        pglove[blockIdx.y * DWG + col] =
            red[threadIdx.x] + red[threadIdx.x + 64] + red[threadIdx.x + 128] + red[threadIdx.x + 192];
    }
}

// ---- combine partials -> avg vector ----
__global__ void k_avg(const float* __restrict__ pglove, const float* __restrict__ pchar,
                      float* __restrict__ avg) {
    const int i = blockIdx.x * 256 + threadIdx.x;
    if (i >= CATD) return;
    float s = 0.0f;
    if (i < DWG) {
        for (int r = 0; r < 16; ++r) s += pglove[r * DWG + i];
    } else {
        const int c = i - DWG;
        for (int r = 0; r < NBLK; ++r) s += pchar[r * HDIM + c];
    }
    avg[i] = s * (1.0f / 4096.0f);
}

__global__ void k_fc1(const float* __restrict__ avg, const float* __restrict__ W,
                      const float* __restrict__ bias, float* __restrict__ h1) {
    const int wave = threadIdx.x >> 6, lane = threadIdx.x & 63;
    const int j = blockIdx.x * 8 + wave;
    const float* w = W + (size_t)j * CATD;
    float s = 0.0f;
    for (int k = lane; k < CATD; k += 64) s += avg[k] * w[k];
#pragma unroll
    for (int o = 32; o > 0; o >>= 1) s += __shfl_down(s, o, 64);
    if (lane == 0) h1[j] = sigf(s + bias[j]);
}

__global__ void k_fc2(const float* __restrict__ h1, const float* __restrict__ W,
                      const float* __restrict__ bias, float* __restrict__ out) {
    const int wave = threadIdx.x >> 6, lane = threadIdx.x & 63;
    const float* w = W + (size_t)wave * HIDD;
    float s = 0.0f;
    for (int k = lane; k < HIDD; k += 64) s += h1[k] * w[k];
#pragma unroll
    for (int o = 32; o > 0; o >>= 1) s += __shfl_down(s, o, 64);
    if (lane == 0) out[wave] = s + bias[wave];
}

extern "C" void kernel_launch(void* const* d_in, const int* in_sizes, int n_in,
                              void* d_out, int out_size, void* d_ws, size_t ws_size,
                              hipStream_t stream) {
    (void)in_sizes; (void)n_in; (void)out_size; (void)ws_size;
    const int*   widx  = (const int*)d_in[0];
    const int*   cidx  = (const int*)d_in[1];
    const int*   clen  = (const int*)d_in[2];
    const float* glove = (const float*)d_in[3];
    const float* cemb  = (const float*)d_in[4];
    const float* wih   = (const float*)d_in[5];
    const float* whh   = (const float*)d_in[6];
    const float* bih   = (const float*)d_in[7];
    const float* bhh   = (const float*)d_in[8];
    const float* fc1W  = (const float*)d_in[9];
    const float* fc1b  = (const float*)d_in[10];
    const float* fc2W  = (const float*)d_in[11];
    const float* fc2b  = (const float*)d_in[12];
    float* out = (float*)d_out;

    char* ws = (char*)d_ws;
    __hip_bfloat16* wt     = (__hip_bfloat16*)(ws);                         // 2 MB
    __hip_bfloat16* cproj  = (__hip_bfloat16*)(ws + (2u << 20));            // 400 KB
    float*          pchar  = (float*)(ws + (2u << 20) + (512u << 10));      // 256 KB
    float*          pglove = (float*)(ws + (2u << 20) + (768u << 10));      // 19.2 KB
    float*          avg    = (float*)(ws + (2u << 20) + (800u << 10));      // 3.2 KB
    float*          h1g    = (float*)(ws + (2u << 20) + (808u << 10));      // 2 KB

    k_convert_wtile<<<256, 256, 0, stream>>>(whh, wt);
    k_char_proj<<<VCC, 256, 0, stream>>>(cemb, wih, bih, bhh, cproj);
    k_lstm_block<<<NBLK, 512, 131072, stream>>>(wt, cproj, cidx, clen, pchar);
    k_sum_glove<<<dim3(5, 16), 256, 0, stream>>>(glove, widx, pglove);
    k_avg<<<4, 256, 0, stream>>>(pglove, pchar, avg);
    k_fc1<<<64, 512, 0, stream>>>(avg, fc1W, fc1b, h1g);
    k_fc2<<<1, 320, 0, stream>>>(h1g, fc2W, fc2b, out);
}

// Round 7
// 2378.202 us; speedup vs baseline: 1.3576x; 1.3576x over previous
//
#include <hip/hip_runtime.h>
#include <hip/hip_bf16.h>
#include <stdint.h>
#include <stddef.h>

#define NW    4096
#define LSEQ  24
#define HDIM  512
#define DWG   300
#define DCC   128
#define VCC   100
#define G4H   2048
#define CATD  812
#define HIDD  512
#define NOUT  5
#define NBLK  128   // LSTM blocks (32 rows each, no cross-block deps)

typedef __bf16 bf16x8 __attribute__((ext_vector_type(8)));
typedef float  f32x16 __attribute__((ext_vector_type(16)));

__device__ __forceinline__ float frcp(float x) { return __builtin_amdgcn_rcpf(x); }
__device__ __forceinline__ float sigf(float x) { return frcp(1.0f + __expf(-x)); }
__device__ __forceinline__ float tanh_fast(float x) { return fmaf(2.0f, frcp(1.0f + __expf(-2.0f * x)), -1.0f); }

// async 16B global->LDS; LDS dest = wave-uniform base + lane*16, global src per-lane
__device__ __forceinline__ void gload16(const void* g, void* l) {
    __builtin_amdgcn_global_load_lds(
        (const __attribute__((address_space(1))) void*)g,
        (__attribute__((address_space(3))) void*)l, 16, 0, 0);
}

// ---- retile W_hh f32 [2048][512] -> bf16 in EXACT staging/ds_read order ----
// wt element layout: [chunk o=(a,kp) 64][wave w 8][frag f=(p,gg) 4][lane 64] x 8 bf16.
// content[o][w][f][lane] = W_hh[(a+2*gg)*512 + (w*2+p)*32 + l31][kp*16 + lhi*8 + 0..7]
__global__ void k_convert_wtile(const float* __restrict__ whh, __hip_bfloat16* __restrict__ wt) {
    const int tid = blockIdx.x * 256 + threadIdx.x;   // 131072
    const int lane = tid & 63, f = (tid >> 6) & 3, w = (tid >> 8) & 7, o = tid >> 11;
    const int a = o >> 5, kp = o & 31;
    const int p = f >> 1, gg = f & 1;
    const int l31 = lane & 31, lhi = lane >> 5;
    const int j = (a + 2 * gg) * 512 + (w * 2 + p) * 32 + l31;
    const int k = kp * 16 + lhi * 8;
    const float* src = whh + (size_t)j * HDIM + k;
    union { bf16x8 v; __hip_bfloat16 e[8]; } u;
#pragma unroll
    for (int i = 0; i < 2; ++i) {
        const float4 fv = *reinterpret_cast<const float4*>(src + i * 4);
        u.e[i * 4 + 0] = __float2bfloat16(fv.x);
        u.e[i * 4 + 1] = __float2bfloat16(fv.y);
        u.e[i * 4 + 2] = __float2bfloat16(fv.z);
        u.e[i * 4 + 3] = __float2bfloat16(fv.w);
    }
    *reinterpret_cast<bf16x8*>(wt + (size_t)tid * 8) = u.v;
}

// ---- char_proj[c][j] = char_embed[c,:] @ W_ih[j,:] + b_ih[j] + b_hh[j]  (bf16 out) ----
__global__ void k_char_proj(const float* __restrict__ cemb, const float* __restrict__ wih,
                            const float* __restrict__ bih, const float* __restrict__ bhh,
                            __hip_bfloat16* __restrict__ cproj) {
    __shared__ float emb[DCC];
    const int c = blockIdx.x;
    if (threadIdx.x < DCC) emb[threadIdx.x] = cemb[c * DCC + threadIdx.x];
    __syncthreads();
    for (int j = threadIdx.x; j < G4H; j += blockDim.x) {
        const float* w = wih + (size_t)j * DCC;
        float acc = bih[j] + bhh[j];
#pragma unroll 4
        for (int k = 0; k < DCC; ++k) acc = fmaf(emb[k], w[k], acc);
        cproj[(size_t)c * G4H + j] = __float2bfloat16(acc);
    }
}

// h swizzle: element (row, col) at byte row*1024 + ((col*2) ^ ((row&7)<<4))
__device__ __forceinline__ int hsw(int row, int col) {
    return (row << 10) + (((col << 1)) ^ ((row & 7) << 4));
}

// ---- LSTM: 128 blocks x 512 thr (8 waves, 2/SIMD). LDS 128KB: 32KB h (single, swizzled)
// + 8 waves x 3 x 4KB wave-private W chunk buffers. W streamed via global_load_lds with
// counted vmcnt(8) (3-deep rotation, never drained). 2 raw lgkm-only barriers per step.
__global__ void __launch_bounds__(512, 2) k_lstm_block(
        const __hip_bfloat16* __restrict__ wt,     // retiled W (see k_convert_wtile)
        const __hip_bfloat16* __restrict__ cproj,  // [100][2048] bf16
        const int* __restrict__ cidx,              // [NW][LSEQ]
        const int* __restrict__ clen,              // [NW]
        float* __restrict__ pchar) {               // [NBLK][512] partial col sums
    extern __shared__ char lds[];
    const int b = blockIdx.x;
    const int tid = threadIdx.x;
    const int w = tid >> 6, lane = tid & 63;
    const int l31 = lane & 31, lhi = lane >> 5;
    const int n0 = b * 32;
    const int xrh = (l31 & 7) << 4;

    char* hb  = lds;                                  // 32 KB h
    char* myW = lds + 32768 + w * 12288;              // wave-private 3 x 4 KB
    const char* wtg = (const char*)wt + w * 4096 + lane * 16;  // per-lane global base

    // pack 16 char-lengths into 4 regs (1 byte each)
    int lp[4];
#pragma unroll
    for (int j = 0; j < 4; ++j) {
        int v = 0;
#pragma unroll
        for (int k = 0; k < 4; ++k) {
            const int len = clen[n0 + j * 8 + (lhi << 2) + k];
            v |= (len & 0xff) << (k * 8);
        }
        lp[j] = v;
    }

    float cs[2][16];
#pragma unroll
    for (int p = 0; p < 2; ++p)
#pragma unroll
        for (int q = 0; q < 16; ++q) cs[p][q] = 0.0f;

    int bi = 1;  // slot of last issued chunk
    // issue chunk m (mod 64) into slot
    auto issue = [&](int m, int slot) {
        const char* gs = wtg + (size_t)(m & 63) * 32768;
        char* ls = myW + slot * 4096;
#pragma unroll
        for (int f = 0; f < 4; ++f) gload16(gs + f * 1024, ls + f * 1024);
    };

    // prologue: chunks 0,1 -> slots 0,1 (8 loads in flight)
    issue(0, 0);
    issue(1, 1);

    int ci16[16];
#pragma unroll
    for (int q = 0; q < 16; ++q) {
        const int rin = (q & 3) + ((q >> 2) << 3) + (lhi << 2);
        ci16[q] = cidx[(n0 + rin) * LSEQ];
    }

    // ---- t = 0: gates from cproj only (h=0,c=0); write full h1 ----
#pragma unroll
    for (int p = 0; p < 2; ++p) {
        const int colh = ((w << 1) + p) * 32 + l31;
#pragma unroll
        for (int q = 0; q < 16; ++q) {
            const int rin = (q & 3) + ((q >> 2) << 3) + (lhi << 2);
            const int lenq = (lp[q >> 2] >> ((q & 3) * 8)) & 0xff;
            float hv = 0.0f;
            if (0 < lenq) {
                const __hip_bfloat16* cp = cproj + ((size_t)ci16[q] << 11) + colh;
                const float i_s = sigf(__bfloat162float(cp[0]));
                const float g_t = tanh_fast(__bfloat162float(cp[1024]));
                const float o_s = sigf(__bfloat162float(cp[1536]));
                const float cn = i_s * g_t;
                cs[p][q] = cn;
                hv = o_s * tanh_fast(cn);
            }
            *reinterpret_cast<__hip_bfloat16*>(hb + hsw(rin, colh)) = __float2bfloat16(hv);
        }
    }
    asm volatile("s_waitcnt lgkmcnt(0)\n\ts_barrier" ::: "memory");

    // kp-loop for one pass: consume 32 chunks, keep issuing 2 ahead
    auto run_pass = [&](int a, f32x16* acc) {
#pragma unroll
        for (int kp = 0; kp < 32; ++kp) {
            bi = (bi == 2) ? 0 : bi + 1;
            issue((a << 5) + kp + 2, bi);
            asm volatile("s_waitcnt vmcnt(8)" ::: "memory");
            const int cslot = (bi == 2) ? 0 : bi + 1;
            const char* wb = myW + cslot * 4096;
            const bf16x8 av = *reinterpret_cast<const bf16x8*>(
                hb + (l31 << 10) + (((kp << 5) | (lhi << 4)) ^ xrh));
#pragma unroll
            for (int p = 0; p < 2; ++p)
#pragma unroll
                for (int g = 0; g < 2; ++g) {
                    const bf16x8 bv = *reinterpret_cast<const bf16x8*>(
                        wb + (p * 2 + g) * 1024 + lane * 16);
                    acc[p * 2 + g] = __builtin_amdgcn_mfma_f32_32x32x16_bf16(
                        av, bv, acc[p * 2 + g], 0, 0, 0);
                }
        }
    };

    for (int t = 1; t < LSEQ; ++t) {
        // cidx for this step (latency hides under pass A)
#pragma unroll
        for (int q = 0; q < 16; ++q) {
            const int rin = (q & 3) + ((q >> 2) << 3) + (lhi << 2);
            ci16[q] = cidx[(n0 + rin) * LSEQ + t];
        }
        float ig[2][16];

        // ---------- pass A: gates i (cp[0]) and g (cp[1024]) ----------
        {
            f32x16 acc[4] = {};
            run_pass(0, acc);
#pragma unroll
            for (int p = 0; p < 2; ++p) {
                const int colh = ((w << 1) + p) * 32 + l31;
#pragma unroll
                for (int q = 0; q < 16; ++q) {
                    const int lenq = (lp[q >> 2] >> ((q & 3) * 8)) & 0xff;
                    ig[p][q] = 0.0f;
                    if (t < lenq) {
                        const __hip_bfloat16* cp = cproj + ((size_t)ci16[q] << 11) + colh;
                        const float gi = acc[p * 2 + 0][q] + __bfloat162float(cp[0]);
                        const float gg = acc[p * 2 + 1][q] + __bfloat162float(cp[1024]);
                        ig[p][q] = sigf(gi) * tanh_fast(gg);
                    }
                }
            }
        }

        // ---------- pass B: gates f (cp[512]) and o (cp[1536]) + update ----------
        {
            f32x16 acc[4] = {};
            run_pass(1, acc);
            // barrier-1: all waves done reading h_t
            asm volatile("s_waitcnt lgkmcnt(0)\n\ts_barrier" ::: "memory");
#pragma unroll
            for (int p = 0; p < 2; ++p) {
                const int colh = ((w << 1) + p) * 32 + l31;
#pragma unroll
                for (int q = 0; q < 16; ++q) {
                    const int lenq = (lp[q >> 2] >> ((q & 3) * 8)) & 0xff;
                    if (t < lenq) {
                        const int rin = (q & 3) + ((q >> 2) << 3) + (lhi << 2);
                        const __hip_bfloat16* cp = cproj + ((size_t)ci16[q] << 11) + colh;
                        const float f_s = sigf(acc[p * 2 + 0][q] + __bfloat162float(cp[512]));
                        const float o_s = sigf(acc[p * 2 + 1][q] + __bfloat162float(cp[1536]));
                        const float cn = fmaf(f_s, cs[p][q], ig[p][q]);
                        cs[p][q] = cn;
                        *reinterpret_cast<__hip_bfloat16*>(hb + hsw(rin, colh)) =
                            __float2bfloat16(o_s * tanh_fast(cn));
                    }   // frozen rows: value already in place (single buffer)
                }
            }
            // barrier-2: h_{t+1} visible
            asm volatile("s_waitcnt lgkmcnt(0)\n\ts_barrier" ::: "memory");
        }
    }

    // block-local masked column partial sums (each thread reads cells it owns)
#pragma unroll
    for (int p = 0; p < 2; ++p) {
        const int colh = ((w << 1) + p) * 32 + l31;
        float s = 0.0f;
#pragma unroll
        for (int q = 0; q < 16; ++q) {
            const int lenq = (lp[q >> 2] >> ((q & 3) * 8)) & 0xff;
            if (lenq >= 2) {
                const int rin = (q & 3) + ((q >> 2) << 3) + (lhi << 2);
                s += __bfloat162float(
                    *reinterpret_cast<const __hip_bfloat16*>(hb + hsw(rin, colh)));
            }
        }
        s += __shfl_xor(s, 32, 64);
        if (lhi == 0) pchar[b * HDIM + colh] = s;
    }
}

// ---- glove gather column sums, 5x16 partial grid ----
__global__ void k_sum_glove(const float* __restrict__ gt, const int* __restrict__ widx,
                            float* __restrict__ pglove) {
    const int col = blockIdx.x * 64 + (threadIdx.x & 63);
    const int phase = threadIdx.x >> 6;
    const int nbase = blockIdx.y * 256;
    float s = 0.0f;
    if (col < DWG) {
        for (int n = nbase + phase; n < nbase + 256; n += 4) {
            s += gt[(size_t)widx[n] * DWG + col];
        }
    }
    __shared__ float red[256];
    red[threadIdx.x] = s;
    __syncthreads();
    if (phase == 0 && col < DWG) {
        pglove[blockIdx.y * DWG + col] =
            red[threadIdx.x] + red[threadIdx.x + 64] + red[threadIdx.x + 128] + red[threadIdx.x + 192];
    }
}

// ---- combine partials -> avg vector ----
__global__ void k_avg(const float* __restrict__ pglove, const float* __restrict__ pchar,
                      float* __restrict__ avg) {
    const int i = blockIdx.x * 256 + threadIdx.x;
    if (i >= CATD) return;
    float s = 0.0f;
    if (i < DWG) {
        for (int r = 0; r < 16; ++r) s += pglove[r * DWG + i];
    } else {
        const int c = i - DWG;
        for (int r = 0; r < NBLK; ++r) s += pchar[r * HDIM + c];
    }
    avg[i] = s * (1.0f / 4096.0f);
}

__global__ void k_fc1(const float* __restrict__ avg, const float* __restrict__ W,
                      const float* __restrict__ bias, float* __restrict__ h1) {
    const int wave = threadIdx.x >> 6, lane = threadIdx.x & 63;
    const int j = blockIdx.x * 8 + wave;
    const float* w = W + (size_t)j * CATD;
    float s = 0.0f;
    for (int k = lane; k < CATD; k += 64) s += avg[k] * w[k];
#pragma unroll
    for (int o = 32; o > 0; o >>= 1) s += __shfl_down(s, o, 64);
    if (lane == 0) h1[j] = sigf(s + bias[j]);
}

__global__ void k_fc2(const float* __restrict__ h1, const float* __restrict__ W,
                      const float* __restrict__ bias, float* __restrict__ out) {
    const int wave = threadIdx.x >> 6, lane = threadIdx.x & 63;
    const float* w = W + (size_t)wave * HIDD;
    float s = 0.0f;
    for (int k = lane; k < HIDD; k += 64) s += h1[k] * w[k];
#pragma unroll
    for (int o = 32; o > 0; o >>= 1) s += __shfl_down(s, o, 64);
    if (lane == 0) out[wave] = s + bias[wave];
}

extern "C" void kernel_launch(void* const* d_in, const int* in_sizes, int n_in,
                              void* d_out, int out_size, void* d_ws, size_t ws_size,
                              hipStream_t stream) {
    (void)in_sizes; (void)n_in; (void)out_size; (void)ws_size;
    const int*   widx  = (const int*)d_in[0];
    const int*   cidx  = (const int*)d_in[1];
    const int*   clen  = (const int*)d_in[2];
    const float* glove = (const float*)d_in[3];
    const float* cemb  = (const float*)d_in[4];
    const float* wih   = (const float*)d_in[5];
    const float* whh   = (const float*)d_in[6];
    const float* bih   = (const float*)d_in[7];
    const float* bhh   = (const float*)d_in[8];
    const float* fc1W  = (const float*)d_in[9];
    const float* fc1b  = (const float*)d_in[10];
    const float* fc2W  = (const float*)d_in[11];
    const float* fc2b  = (const float*)d_in[12];
    float* out = (float*)d_out;

    char* ws = (char*)d_ws;
    __hip_bfloat16* wt     = (__hip_bfloat16*)(ws);                         // 2 MB
    __hip_bfloat16* cproj  = (__hip_bfloat16*)(ws + (2u << 20));            // 400 KB
    float*          pchar  = (float*)(ws + (2u << 20) + (512u << 10));      // 256 KB
    float*          pglove = (float*)(ws + (2u << 20) + (768u << 10));      // 19.2 KB
    float*          avg    = (float*)(ws + (2u << 20) + (800u << 10));      // 3.2 KB
    float*          h1g    = (float*)(ws + (2u << 20) + (808u << 10));      // 2 KB

    k_convert_wtile<<<512, 256, 0, stream>>>(whh, wt);
    k_char_proj<<<VCC, 256, 0, stream>>>(cemb, wih, bih, bhh, cproj);
    k_lstm_block<<<NBLK, 512, 131072, stream>>>(wt, cproj, cidx, clen, pchar);
    k_sum_glove<<<dim3(5, 16), 256, 0, stream>>>(glove, widx, pglove);
    k_avg<<<4, 256, 0, stream>>>(pglove, pchar, avg);
    k_fc1<<<64, 512, 0, stream>>>(avg, fc1W, fc1b, h1g);
    k_fc2<<<1, 320, 0, stream>>>(h1g, fc2W, fc2b, out);
}

// Round 8
// 758.494 us; speedup vs baseline: 4.2567x; 3.1354x over previous
//
#include <hip/hip_runtime.h>
#include <hip/hip_bf16.h>
#include <stdint.h>
#include <stddef.h>

#define NW    4096
#define LSEQ  24
#define HDIM  512
#define DWG   300
#define DCC   128
#define VCC   100
#define G4H   2048
#define CATD  812
#define HIDD  512
#define NOUT  5
#define NBLK  128   // LSTM blocks (32 rows each, no cross-block deps)

typedef __bf16 bf16x8 __attribute__((ext_vector_type(8)));
typedef float  f32x16 __attribute__((ext_vector_type(16)));

__device__ __forceinline__ float frcp(float x) { return __builtin_amdgcn_rcpf(x); }
__device__ __forceinline__ float sigf(float x) { return frcp(1.0f + __expf(-x)); }
__device__ __forceinline__ float tanh_fast(float x) { return fmaf(2.0f, frcp(1.0f + __expf(-2.0f * x)), -1.0f); }

// ---- retile W_hh f32 [2048][512] -> bf16 in EXACT per-wave read order ----
// wt layout: [chunk o=(a,kp) 64][wave w 8][frag f=(p,gg) 4][lane 64] x 8 bf16 (chunk=32KB).
// content[o][w][f][lane] = W_hh[(a+2*gg)*512 + (w*2+p)*32 + l31][kp*16 + lhi*8 + 0..7]
// (validated on-device in R7, absmax 0)
__global__ void k_convert_wtile(const float* __restrict__ whh, __hip_bfloat16* __restrict__ wt) {
    const int tid = blockIdx.x * 256 + threadIdx.x;   // 131072
    const int lane = tid & 63, f = (tid >> 6) & 3, w = (tid >> 8) & 7, o = tid >> 11;
    const int a = o >> 5, kp = o & 31;
    const int p = f >> 1, gg = f & 1;
    const int l31 = lane & 31, lhi = lane >> 5;
    const int j = (a + 2 * gg) * 512 + (w * 2 + p) * 32 + l31;
    const int k = kp * 16 + lhi * 8;
    const float* src = whh + (size_t)j * HDIM + k;
    union { bf16x8 v; __hip_bfloat16 e[8]; } u;
#pragma unroll
    for (int i = 0; i < 2; ++i) {
        const float4 fv = *reinterpret_cast<const float4*>(src + i * 4);
        u.e[i * 4 + 0] = __float2bfloat16(fv.x);
        u.e[i * 4 + 1] = __float2bfloat16(fv.y);
        u.e[i * 4 + 2] = __float2bfloat16(fv.z);
        u.e[i * 4 + 3] = __float2bfloat16(fv.w);
    }
    *reinterpret_cast<bf16x8*>(wt + (size_t)tid * 8) = u.v;
}

// ---- char_proj[c][j] = char_embed[c,:] @ W_ih[j,:] + b_ih[j] + b_hh[j]  (bf16 out) ----
__global__ void k_char_proj(const float* __restrict__ cemb, const float* __restrict__ wih,
                            const float* __restrict__ bih, const float* __restrict__ bhh,
                            __hip_bfloat16* __restrict__ cproj) {
    __shared__ float emb[DCC];
    const int c = blockIdx.x;
    if (threadIdx.x < DCC) emb[threadIdx.x] = cemb[c * DCC + threadIdx.x];
    __syncthreads();
    for (int j = threadIdx.x; j < G4H; j += blockDim.x) {
        const float* w = wih + (size_t)j * DCC;
        float acc = bih[j] + bhh[j];
#pragma unroll 4
        for (int k = 0; k < DCC; ++k) acc = fmaf(emb[k], w[k], acc);
        cproj[(size_t)c * G4H + j] = __float2bfloat16(acc);
    }
}

// h swizzle (R3-proven, 0 bank conflicts): (row,col) at byte row*1024 + ((col*2)^((row&15)<<4))
__device__ __forceinline__ int hsw(int row, int col) {
    return (row << 10) + (((col << 1)) ^ ((row & 15) << 4));
}

#define RIN(q) (((q) & 3) + (((q) >> 2) << 3) + (lhi << 2))
#define LENQ(q) ((lp[(q) >> 2] >> (((q) & 3) * 8)) & 0xff)

// ---- LSTM: 128 blocks x 512 thr (8 waves, 2/SIMD). h in single swizzled 32KB LDS buffer.
// W streamed L2->VGPR with 2-slot named-register prefetch (no lambdas/asm; spill-free).
// Two gate passes per step (i,g then f,o); 2 plain __syncthreads per step.
__global__ void __launch_bounds__(512, 2) k_lstm_block(
        const __hip_bfloat16* __restrict__ wt,     // retiled W (see k_convert_wtile)
        const __hip_bfloat16* __restrict__ cproj,  // [100][2048] bf16
        const int* __restrict__ cidx,              // [NW][LSEQ]
        const int* __restrict__ clen,              // [NW]
        float* __restrict__ pchar) {               // [NBLK][512] partial col sums
    __shared__ char hb[32768];
    const int b = blockIdx.x;
    const int tid = threadIdx.x;
    const int w = tid >> 6, lane = tid & 63;
    const int l31 = lane & 31, lhi = lane >> 5;
    const int n0 = b * 32;
    const int xr = (l31 & 15) << 4;

    const char* wbase = (const char*)wt + w * 4096 + lane * 16;   // + chunk*32768 + f*1024

    int lp[4];
#pragma unroll
    for (int j = 0; j < 4; ++j) {
        int v = 0;
#pragma unroll
        for (int k = 0; k < 4; ++k) v |= (clen[n0 + j * 8 + (lhi << 2) + k] & 0xff) << (k * 8);
        lp[j] = v;
    }

    float cs[2][16];
#pragma unroll
    for (int p = 0; p < 2; ++p)
#pragma unroll
        for (int q = 0; q < 16; ++q) cs[p][q] = 0.0f;

    int ci16[16];
#pragma unroll
    for (int q = 0; q < 16; ++q) ci16[q] = cidx[(n0 + RIN(q)) * LSEQ];

    // ---- t = 0: h,c = 0 -> gates from cproj only; write full h1 ----
#pragma unroll
    for (int p = 0; p < 2; ++p) {
        const int colh = ((w << 1) + p) * 32 + l31;
#pragma unroll
        for (int q = 0; q < 16; ++q) {
            float hv = 0.0f;
            if (0 < LENQ(q)) {
                const __hip_bfloat16* cp = cproj + ((size_t)ci16[q] << 11) + colh;
                const float i_s = sigf(__bfloat162float(cp[0]));
                const float g_t = tanh_fast(__bfloat162float(cp[1024]));
                const float o_s = sigf(__bfloat162float(cp[1536]));
                const float cn = i_s * g_t;
                cs[p][q] = cn;
                hv = o_s * tanh_fast(cn);
            }
            *reinterpret_cast<__hip_bfloat16*>(hb + hsw(RIN(q), colh)) = __float2bfloat16(hv);
        }
    }
    __syncthreads();

    for (int t = 1; t < LSEQ; ++t) {
#pragma unroll
        for (int q = 0; q < 16; ++q) ci16[q] = cidx[(n0 + RIN(q)) * LSEQ + t];

        float ig[2][16];

        // ================= pass A: gates i, g (chunks 0..31) =================
        {
            f32x16 a00 = {}, a01 = {}, a10 = {}, a11 = {};   // [p][i|g]
            const char* cb = wbase;                           // chunk 0
            bf16x8 pA0 = *reinterpret_cast<const bf16x8*>(cb);
            bf16x8 pA1 = *reinterpret_cast<const bf16x8*>(cb + 1024);
            bf16x8 pA2 = *reinterpret_cast<const bf16x8*>(cb + 2048);
            bf16x8 pA3 = *reinterpret_cast<const bf16x8*>(cb + 3072);
            cb += 32768;
            bf16x8 pB0 = *reinterpret_cast<const bf16x8*>(cb);
            bf16x8 pB1 = *reinterpret_cast<const bf16x8*>(cb + 1024);
            bf16x8 pB2 = *reinterpret_cast<const bf16x8*>(cb + 2048);
            bf16x8 pB3 = *reinterpret_cast<const bf16x8*>(cb + 3072);
#pragma unroll 2
            for (int kp2 = 0; kp2 < 16; ++kp2) {
                const int kp = kp2 * 2;
                {
                    const bf16x8 av = *reinterpret_cast<const bf16x8*>(
                        hb + (l31 << 10) + (((kp << 5) | (lhi << 4)) ^ xr));
                    a00 = __builtin_amdgcn_mfma_f32_32x32x16_bf16(av, pA0, a00, 0, 0, 0);
                    a01 = __builtin_amdgcn_mfma_f32_32x32x16_bf16(av, pA1, a01, 0, 0, 0);
                    a10 = __builtin_amdgcn_mfma_f32_32x32x16_bf16(av, pA2, a10, 0, 0, 0);
                    a11 = __builtin_amdgcn_mfma_f32_32x32x16_bf16(av, pA3, a11, 0, 0, 0);
                    const char* nc = wbase + (size_t)((kp + 2) & 63) * 32768;
                    pA0 = *reinterpret_cast<const bf16x8*>(nc);
                    pA1 = *reinterpret_cast<const bf16x8*>(nc + 1024);
                    pA2 = *reinterpret_cast<const bf16x8*>(nc + 2048);
                    pA3 = *reinterpret_cast<const bf16x8*>(nc + 3072);
                }
                {
                    const bf16x8 av = *reinterpret_cast<const bf16x8*>(
                        hb + (l31 << 10) + ((((kp + 1) << 5) | (lhi << 4)) ^ xr));
                    a00 = __builtin_amdgcn_mfma_f32_32x32x16_bf16(av, pB0, a00, 0, 0, 0);
                    a01 = __builtin_amdgcn_mfma_f32_32x32x16_bf16(av, pB1, a01, 0, 0, 0);
                    a10 = __builtin_amdgcn_mfma_f32_32x32x16_bf16(av, pB2, a10, 0, 0, 0);
                    a11 = __builtin_amdgcn_mfma_f32_32x32x16_bf16(av, pB3, a11, 0, 0, 0);
                    const char* nc = wbase + (size_t)((kp + 3) & 63) * 32768;
                    pB0 = *reinterpret_cast<const bf16x8*>(nc);
                    pB1 = *reinterpret_cast<const bf16x8*>(nc + 1024);
                    pB2 = *reinterpret_cast<const bf16x8*>(nc + 2048);
                    pB3 = *reinterpret_cast<const bf16x8*>(nc + 3072);
                }
            }
            // epilogue A: ig = sig(i)*tanh(g) for active rows
#pragma unroll
            for (int p = 0; p < 2; ++p) {
                const int colh = ((w << 1) + p) * 32 + l31;
                const f32x16& ai = p ? a10 : a00;
                const f32x16& ag = p ? a11 : a01;
#pragma unroll
                for (int q = 0; q < 16; ++q) {
                    float v = 0.0f;
                    if (t < LENQ(q)) {
                        const __hip_bfloat16* cp = cproj + ((size_t)ci16[q] << 11) + colh;
                        v = sigf(ai[q] + __bfloat162float(cp[0])) *
                            tanh_fast(ag[q] + __bfloat162float(cp[1024]));
                    }
                    ig[p][q] = v;
                }
            }
        }

        // ================= pass B: gates f, o (chunks 32..63) + update =================
        {
            f32x16 a00 = {}, a01 = {}, a10 = {}, a11 = {};   // [p][f|o]
            const char* cb = wbase + 32 * 32768;
            bf16x8 pA0 = *reinterpret_cast<const bf16x8*>(cb);
            bf16x8 pA1 = *reinterpret_cast<const bf16x8*>(cb + 1024);
            bf16x8 pA2 = *reinterpret_cast<const bf16x8*>(cb + 2048);
            bf16x8 pA3 = *reinterpret_cast<const bf16x8*>(cb + 3072);
            cb += 32768;
            bf16x8 pB0 = *reinterpret_cast<const bf16x8*>(cb);
            bf16x8 pB1 = *reinterpret_cast<const bf16x8*>(cb + 1024);
            bf16x8 pB2 = *reinterpret_cast<const bf16x8*>(cb + 2048);
            bf16x8 pB3 = *reinterpret_cast<const bf16x8*>(cb + 3072);
#pragma unroll 2
            for (int kp2 = 0; kp2 < 16; ++kp2) {
                const int kp = kp2 * 2;
                {
                    const bf16x8 av = *reinterpret_cast<const bf16x8*>(
                        hb + (l31 << 10) + (((kp << 5) | (lhi << 4)) ^ xr));
                    a00 = __builtin_amdgcn_mfma_f32_32x32x16_bf16(av, pA0, a00, 0, 0, 0);
                    a01 = __builtin_amdgcn_mfma_f32_32x32x16_bf16(av, pA1, a01, 0, 0, 0);
                    a10 = __builtin_amdgcn_mfma_f32_32x32x16_bf16(av, pA2, a10, 0, 0, 0);
                    a11 = __builtin_amdgcn_mfma_f32_32x32x16_bf16(av, pA3, a11, 0, 0, 0);
                    const char* nc = wbase + (size_t)((32 + kp + 2) & 63) * 32768;
                    pA0 = *reinterpret_cast<const bf16x8*>(nc);
                    pA1 = *reinterpret_cast<const bf16x8*>(nc + 1024);
                    pA2 = *reinterpret_cast<const bf16x8*>(nc + 2048);
                    pA3 = *reinterpret_cast<const bf16x8*>(nc + 3072);
                }
                {
                    const bf16x8 av = *reinterpret_cast<const bf16x8*>(
                        hb + (l31 << 10) + ((((kp + 1) << 5) | (lhi << 4)) ^ xr));
                    a00 = __builtin_amdgcn_mfma_f32_32x32x16_bf16(av, pB0, a00, 0, 0, 0);
                    a01 = __builtin_amdgcn_mfma_f32_32x32x16_bf16(av, pB1, a01, 0, 0, 0);
                    a10 = __builtin_amdgcn_mfma_f32_32x32x16_bf16(av, pB2, a10, 0, 0, 0);
                    a11 = __builtin_amdgcn_mfma_f32_32x32x16_bf16(av, pB3, a11, 0, 0, 0);
                    const char* nc = wbase + (size_t)((32 + kp + 3) & 63) * 32768;
                    pB0 = *reinterpret_cast<const bf16x8*>(nc);
                    pB1 = *reinterpret_cast<const bf16x8*>(nc + 1024);
                    pB2 = *reinterpret_cast<const bf16x8*>(nc + 2048);
                    pB3 = *reinterpret_cast<const bf16x8*>(nc + 3072);
                }
            }
            __syncthreads();   // all waves done reading h_t
#pragma unroll
            for (int p = 0; p < 2; ++p) {
                const int colh = ((w << 1) + p) * 32 + l31;
                const f32x16& af = p ? a10 : a00;
                const f32x16& ao = p ? a11 : a01;
#pragma unroll
                for (int q = 0; q < 16; ++q) {
                    if (t < LENQ(q)) {
                        const __hip_bfloat16* cp = cproj + ((size_t)ci16[q] << 11) + colh;
                        const float f_s = sigf(af[q] + __bfloat162float(cp[512]));
                        const float o_s = sigf(ao[q] + __bfloat162float(cp[1536]));
                        const float cn = fmaf(f_s, cs[p][q], ig[p][q]);
                        cs[p][q] = cn;
                        *reinterpret_cast<__hip_bfloat16*>(hb + hsw(RIN(q), colh)) =
                            __float2bfloat16(o_s * tanh_fast(cn));
                    }   // frozen rows keep old value (single buffer)
                }
            }
            __syncthreads();   // h_{t+1} visible
        }
    }

    // block-local masked column partial sums (thread reads only cells it owns)
#pragma unroll
    for (int p = 0; p < 2; ++p) {
        const int colh = ((w << 1) + p) * 32 + l31;
        float s = 0.0f;
#pragma unroll
        for (int q = 0; q < 16; ++q) {
            if (LENQ(q) >= 2) {
                s += __bfloat162float(
                    *reinterpret_cast<const __hip_bfloat16*>(hb + hsw(RIN(q), colh)));
            }
        }
        s += __shfl_xor(s, 32, 64);
        if (lhi == 0) pchar[b * HDIM + colh] = s;
    }
}

// ---- glove gather column sums, 5x16 partial grid ----
__global__ void k_sum_glove(const float* __restrict__ gt, const int* __restrict__ widx,
                            float* __restrict__ pglove) {
    const int col = blockIdx.x * 64 + (threadIdx.x & 63);
    const int phase = threadIdx.x >> 6;
    const int nbase = blockIdx.y * 256;
    float s = 0.0f;
    if (col < DWG) {
        for (int n = nbase + phase; n < nbase + 256; n += 4) {
            s += gt[(size_t)widx[n] * DWG + col];
        }
    }
    __shared__ float red[256];
    red[threadIdx.x] = s;
    __syncthreads();
    if (phase == 0 && col < DWG) {
        pglove[blockIdx.y * DWG + col] =
            red[threadIdx.x] + red[threadIdx.x + 64] + red[threadIdx.x + 128] + red[threadIdx.x + 192];
    }
}

// ---- combine partials -> avg vector ----
__global__ void k_avg(const float* __restrict__ pglove, const float* __restrict__ pchar,
                      float* __restrict__ avg) {
    const int i = blockIdx.x * 256 + threadIdx.x;
    if (i >= CATD) return;
    float s = 0.0f;
    if (i < DWG) {
        for (int r = 0; r < 16; ++r) s += pglove[r * DWG + i];
    } else {
        const int c = i - DWG;
        for (int r = 0; r < NBLK; ++r) s += pchar[r * HDIM + c];
    }
    avg[i] = s * (1.0f / 4096.0f);
}

__global__ void k_fc1(const float* __restrict__ avg, const float* __restrict__ W,
                      const float* __restrict__ bias, float* __restrict__ h1) {
    const int wave = threadIdx.x >> 6, lane = threadIdx.x & 63;
    const int j = blockIdx.x * 8 + wave;
    const float* w = W + (size_t)j * CATD;
    float s = 0.0f;
    for (int k = lane; k < CATD; k += 64) s += avg[k] * w[k];
#pragma unroll
    for (int o = 32; o > 0; o >>= 1) s += __shfl_down(s, o, 64);
    if (lane == 0) h1[j] = sigf(s + bias[j]);
}

__global__ void k_fc2(const float* __restrict__ h1, const float* __restrict__ W,
                      const float* __restrict__ bias, float* __restrict__ out) {
    const int wave = threadIdx.x >> 6, lane = threadIdx.x & 63;
    const float* w = W + (size_t)wave * HIDD;
    float s = 0.0f;
    for (int k = lane; k < HIDD; k += 64) s += h1[k] * w[k];
#pragma unroll
    for (int o = 32; o > 0; o >>= 1) s += __shfl_down(s, o, 64);
    if (lane == 0) out[wave] = s + bias[wave];
}

extern "C" void kernel_launch(void* const* d_in, const int* in_sizes, int n_in,
                              void* d_out, int out_size, void* d_ws, size_t ws_size,
                              hipStream_t stream) {
    (void)in_sizes; (void)n_in; (void)out_size; (void)ws_size;
    const int*   widx  = (const int*)d_in[0];
    const int*   cidx  = (const int*)d_in[1];
    const int*   clen  = (const int*)d_in[2];
    const float* glove = (const float*)d_in[3];
    const float* cemb  = (const float*)d_in[4];
    const float* wih   = (const float*)d_in[5];
    const float* whh   = (const float*)d_in[6];
    const float* bih   = (const float*)d_in[7];
    const float* bhh   = (const float*)d_in[8];
    const float* fc1W  = (const float*)d_in[9];
    const float* fc1b  = (const float*)d_in[10];
    const float* fc2W  = (const float*)d_in[11];
    const float* fc2b  = (const float*)d_in[12];
    float* out = (float*)d_out;

    char* ws = (char*)d_ws;
    __hip_bfloat16* wt     = (__hip_bfloat16*)(ws);                         // 2 MB
    __hip_bfloat16* cproj  = (__hip_bfloat16*)(ws + (2u << 20));            // 400 KB
    float*          pchar  = (float*)(ws + (2u << 20) + (512u << 10));      // 256 KB
    float*          pglove = (float*)(ws + (2u << 20) + (768u << 10));      // 19.2 KB
    float*          avg    = (float*)(ws + (2u << 20) + (800u << 10));      // 3.2 KB
    float*          h1g    = (float*)(ws + (2u << 20) + (808u << 10));      // 2 KB

    k_convert_wtile<<<512, 256, 0, stream>>>(whh, wt);
    k_char_proj<<<VCC, 256, 0, stream>>>(cemb, wih, bih, bhh, cproj);
    k_lstm_block<<<NBLK, 512, 0, stream>>>(wt, cproj, cidx, clen, pchar);
    k_sum_glove<<<dim3(5, 16), 256, 0, stream>>>(glove, widx, pglove);
    k_avg<<<4, 256, 0, stream>>>(pglove, pchar, avg);
    k_fc1<<<64, 512, 0, stream>>>(avg, fc1W, fc1b, h1g);
    k_fc2<<<1, 320, 0, stream>>>(h1g, fc2W, fc2b, out);
}